// Round 1
// baseline (317.132 us; speedup 1.0000x reference)
//
#include <hip/hip_runtime.h>
#include <math.h>

#define NBINS 1000
#define NDIM 64
#define ROWS_PER_BLOCK 4

// Prologue: build packed interval table packed[d*(NBINS-1)+i] = (x_i, c_i, x_{i+1}, c_{i+1})
// and per-dim seed (lo, (NBINS-1)/(hi-lo)) for the closed-form searchsorted seed.
__global__ __launch_bounds__(256) void mg_pack(const float* __restrict__ xvals,
                                               const float* __restrict__ cdf,
                                               float4* __restrict__ packed,
                                               float2* __restrict__ seedtab) {
    int t = blockIdx.x * blockDim.x + threadIdx.x;
    const int total = NDIM * (NBINS - 1);
    if (t >= total) return;
    int d = t / (NBINS - 1);
    int i = t - d * (NBINS - 1);
    float x0 = xvals[d * NBINS + i];
    float x1 = xvals[d * NBINS + i + 1];
    float c0 = cdf[d * NBINS + i];
    float c1 = cdf[d * NBINS + i + 1];
    packed[t] = make_float4(x0, c0, x1, c1);
    if (i == 0) {
        float lo = x0;
        float hi = xvals[d * NBINS + NBINS - 1];
        seedtab[d] = make_float2(lo, (float)(NBINS - 1) / (hi - lo));
    }
}

// Main kernel: one wave (64 lanes) per row; lane = dimension.
// x read and z write fully coalesced; log_det via wave shuffle reduction.
template <bool PACKED>
__global__ __launch_bounds__(256) void mg_main(const float* __restrict__ x,
                                               const float* __restrict__ xvals,
                                               const float* __restrict__ cdf,
                                               const float4* __restrict__ packed,
                                               const float2* __restrict__ seedtab,
                                               float* __restrict__ out, int B) {
    int wave = threadIdx.x >> 6;
    int lane = threadIdx.x & 63;
    int row = blockIdx.x * ROWS_PER_BLOCK + wave;
    if (row >= B) return;
    const int d = lane;

    float xv = x[(size_t)row * NDIM + d];

    float lo, invstep;
    if constexpr (PACKED) {
        float2 st = seedtab[d];
        lo = st.x;
        invstep = st.y;
    } else {
        lo = xvals[d * NBINS];
        float hi = xvals[d * NBINS + NBINS - 1];
        invstep = (float)(NBINS - 1) / (hi - lo);
    }

    // Closed-form seed for the interval index (grid is an fp32 linspace),
    // then exact fix-up walk against the real table values so searchsorted
    // semantics (side='left', clip to [1, NBINS-1]) are bit-exact.
    int i = (int)floorf((xv - lo) * invstep);
    i = min(max(i, 0), NBINS - 2);

    float xl, xr, cl, cr;
    auto load_entry = [&](int ii) {
        if constexpr (PACKED) {
            float4 e = packed[d * (NBINS - 1) + ii];
            xl = e.x; cl = e.y; xr = e.z; cr = e.w;
        } else {
            xl = xvals[d * NBINS + ii];
            xr = xvals[d * NBINS + ii + 1];
            cl = cdf[d * NBINS + ii];
            cr = cdf[d * NBINS + ii + 1];
        }
    };

    load_entry(i);
    // correct interval i satisfies: (i==0 || x_i < xv) && (i==NBINS-2 || xv <= x_{i+1})
    while (xv > xr && i < NBINS - 2) { ++i; load_entry(i); }
    while (xv <= xl && i > 0)        { --i; load_entry(i); }

    float denom = (xr - xl) + 1e-12f;
    float slope = (cr - cl) / denom;
    float u = cl + slope * (xv - xl);
    float p_hat = fmaxf(slope, 1e-12f);
    u = fminf(fmaxf(u, 1e-6f), 1.0f - 1e-6f);

    float e1 = fminf(fmaxf(2.0f * u - 1.0f, -0.99999f), 0.99999f);
    float z = 1.4142135623730951f * erfinvf(e1);
    z = fminf(fmaxf(z, -10.0f), 10.0f);

    float phi = 0.3989422804014327f * __expf(-0.5f * z * z);
    float term = __logf(p_hat) - __logf(phi + 1e-12f);

    out[(size_t)row * NDIM + d] = z;

    // wave-level sum over the 64 dims for log_det
#pragma unroll
    for (int off = 32; off > 0; off >>= 1)
        term += __shfl_xor(term, off, 64);
    if (lane == 0) out[(size_t)B * NDIM + row] = term;
}

extern "C" void kernel_launch(void* const* d_in, const int* in_sizes, int n_in,
                              void* d_out, int out_size, void* d_ws, size_t ws_size,
                              hipStream_t stream) {
    const float* x = (const float*)d_in[0];
    const float* xvals = (const float*)d_in[1];
    const float* cdf = (const float*)d_in[2];
    float* out = (float*)d_out;
    int B = in_sizes[0] / NDIM;

    const size_t packed_bytes = (size_t)NDIM * (NBINS - 1) * sizeof(float4);
    const size_t need = packed_bytes + (size_t)NDIM * sizeof(float2);

    dim3 mainGrid((B + ROWS_PER_BLOCK - 1) / ROWS_PER_BLOCK);
    dim3 mainBlock(ROWS_PER_BLOCK * 64);

    if (ws_size >= need) {
        float4* packed = (float4*)d_ws;
        float2* seedtab = (float2*)((char*)d_ws + packed_bytes);
        const int total = NDIM * (NBINS - 1);
        hipLaunchKernelGGL(mg_pack, dim3((total + 255) / 256), dim3(256), 0, stream,
                           xvals, cdf, packed, seedtab);
        hipLaunchKernelGGL((mg_main<true>), mainGrid, mainBlock, 0, stream,
                           x, xvals, cdf, packed, seedtab, out, B);
    } else {
        hipLaunchKernelGGL((mg_main<false>), mainGrid, mainBlock, 0, stream,
                           x, xvals, cdf, (const float4*)nullptr, (const float2*)nullptr, out, B);
    }
}

// Round 2
// 206.260 us; speedup vs baseline: 1.5375x; 1.5375x over previous
//
#include <hip/hip_runtime.h>
#include <math.h>

#define NBINS 1000
#define NDIM 64
#define WAVES_PER_BLOCK 4
// each wave: 4 rows (16 lanes/row), each lane: 4 dims -> block covers 16 rows

// Pack table: entry (x0, x1, c0, slope) per interval; slope precomputed so the
// hot kernel has no divide. Also per-dim seed (lo, (NB-1)/(hi-lo)).
__global__ __launch_bounds__(256) void mg_pack(const float* __restrict__ xvals,
                                               const float* __restrict__ cdf,
                                               float4* __restrict__ packed,
                                               float2* __restrict__ seedtab) {
    int t = blockIdx.x * blockDim.x + threadIdx.x;
    const int total = NDIM * (NBINS - 1);
    if (t >= total) return;
    int d = t / (NBINS - 1);
    int i = t - d * (NBINS - 1);
    float x0 = xvals[d * NBINS + i];
    float x1 = xvals[d * NBINS + i + 1];
    float c0 = cdf[d * NBINS + i];
    float c1 = cdf[d * NBINS + i + 1];
    float slope = (c1 - c0) / ((x1 - x0) + 1e-12f);  // matches ref arithmetic
    packed[t] = make_float4(x0, x1, c0, slope);
    if (i == 0) {
        float lo = x0;
        float hi = xvals[d * NBINS + NBINS - 1];
        seedtab[d] = make_float2(lo, (float)(NBINS - 1) / (hi - lo));
    }
}

template <bool PACKED>
__global__ __launch_bounds__(256) void mg_main(const float* __restrict__ x,
                                               const float* __restrict__ xvals,
                                               const float* __restrict__ cdf,
                                               const float4* __restrict__ packed,
                                               const float2* __restrict__ seedtab,
                                               float* __restrict__ out, int B) {
    const int lane = threadIdx.x & 63;
    const int wave = threadIdx.x >> 6;
    const int g = lane >> 4;      // row within wave
    const int s = lane & 15;      // position within row; dims 4s..4s+3
    const int row = blockIdx.x * (WAVES_PER_BLOCK * 4) + wave * 4 + g;
    if (row >= B) return;
    const int d0 = 4 * s;

    auto load_entry = [&](int dd, int ii) -> float4 {
        if constexpr (PACKED) {
            return packed[dd * (NBINS - 1) + ii];
        } else {
            float x0 = xvals[dd * NBINS + ii];
            float x1 = xvals[dd * NBINS + ii + 1];
            float c0 = cdf[dd * NBINS + ii];
            float c1 = cdf[dd * NBINS + ii + 1];
            return make_float4(x0, x1, c0, (c1 - c0) / ((x1 - x0) + 1e-12f));
        }
    };

    // one coalesced 16B load: 4 dims of this row
    const float4 xq = ((const float4*)x)[(size_t)row * (NDIM / 4) + s];
    float xv[4] = {xq.x, xq.y, xq.z, xq.w};

    // seeds + 4 independent gathers in flight
    int ii[4];
#pragma unroll
    for (int j = 0; j < 4; ++j) {
        float lo, invstep;
        if constexpr (PACKED) {
            float2 st = seedtab[d0 + j];
            lo = st.x; invstep = st.y;
        } else {
            lo = xvals[(d0 + j) * NBINS];
            float hi = xvals[(d0 + j) * NBINS + NBINS - 1];
            invstep = (float)(NBINS - 1) / (hi - lo);
        }
        int i = (int)floorf((xv[j] - lo) * invstep);
        ii[j] = min(max(i, 0), NBINS - 2);
    }
    float4 ent[4];
#pragma unroll
    for (int j = 0; j < 4; ++j) ent[j] = load_entry(d0 + j, ii[j]);

    float zout[4];
    float term = 0.0f;
#pragma unroll
    for (int j = 0; j < 4; ++j) {
        float xl = ent[j].x, xr = ent[j].y, cl = ent[j].z, sl = ent[j].w;
        int i = ii[j];
        // exact searchsorted fix-up (seed is within ~1 bin; loops rarely run)
        while (xv[j] > xr && i < NBINS - 2) {
            ++i; float4 e = load_entry(d0 + j, i);
            xl = e.x; xr = e.y; cl = e.z; sl = e.w;
        }
        while (xv[j] <= xl && i > 0) {
            --i; float4 e = load_entry(d0 + j, i);
            xl = e.x; xr = e.y; cl = e.z; sl = e.w;
        }

        float u = fmaf(sl, xv[j] - xl, cl);
        float p_hat = fmaxf(sl, 1e-12f);
        u = fminf(fmaxf(u, 1e-6f), 1.0f - 1e-6f);
        float e1 = fminf(fmaxf(fmaf(2.0f, u, -1.0f), -0.99999f), 0.99999f);

        // Giles (2012) single-precision erfinv, branchless (both polys + select)
        float wv = -__logf(fmaf(-e1, e1, 1.0f));
        float pc, pt;
        {
            float t = wv - 2.5f;
            pc = 2.81022636e-08f;
            pc = fmaf(pc, t, 3.43273939e-07f);
            pc = fmaf(pc, t, -3.5233877e-06f);
            pc = fmaf(pc, t, -4.39150654e-06f);
            pc = fmaf(pc, t, 0.00021858087f);
            pc = fmaf(pc, t, -0.00125372503f);
            pc = fmaf(pc, t, -0.00417768164f);
            pc = fmaf(pc, t, 0.246640727f);
            pc = fmaf(pc, t, 1.50140941f);
        }
        {
            float t = sqrtf(wv) - 3.0f;
            pt = -0.000200214257f;
            pt = fmaf(pt, t, 0.000100950558f);
            pt = fmaf(pt, t, 0.00134934322f);
            pt = fmaf(pt, t, -0.00367342844f);
            pt = fmaf(pt, t, 0.00573950773f);
            pt = fmaf(pt, t, -0.0076224613f);
            pt = fmaf(pt, t, 0.00943887047f);
            pt = fmaf(pt, t, 1.00167406f);
            pt = fmaf(pt, t, 2.83297682f);
        }
        float p = (wv < 5.0f) ? pc : pt;
        float z = 1.4142135623730951f * p * e1;
        z = fminf(fmaxf(z, -10.0f), 10.0f);
        zout[j] = z;

        // log(p_hat) - log(phi + 1e-12); |z| <= 4.417 so phi >= 2.3e-5 and the
        // +1e-12 is negligible (<=4.3e-8 abs): -log(phi) = 0.91893853 + z^2/2
        term += __logf(p_hat) + fmaf(0.5f * z, z, 0.9189385332046727f);
    }

    ((float4*)out)[(size_t)row * (NDIM / 4) + s] = make_float4(zout[0], zout[1], zout[2], zout[3]);

    // reduce over the 16 lanes of this row (offsets 8,4,2,1 stay in-group)
#pragma unroll
    for (int off = 8; off >= 1; off >>= 1) term += __shfl_xor(term, off, 64);
    if (s == 0) out[(size_t)B * NDIM + row] = term;
}

extern "C" void kernel_launch(void* const* d_in, const int* in_sizes, int n_in,
                              void* d_out, int out_size, void* d_ws, size_t ws_size,
                              hipStream_t stream) {
    const float* x = (const float*)d_in[0];
    const float* xvals = (const float*)d_in[1];
    const float* cdf = (const float*)d_in[2];
    float* out = (float*)d_out;
    int B = in_sizes[0] / NDIM;

    const size_t packed_bytes = (size_t)NDIM * (NBINS - 1) * sizeof(float4);
    const size_t need = packed_bytes + (size_t)NDIM * sizeof(float2);

    const int rows_per_block = WAVES_PER_BLOCK * 4;
    dim3 mainGrid((B + rows_per_block - 1) / rows_per_block);
    dim3 mainBlock(WAVES_PER_BLOCK * 64);

    if (ws_size >= need) {
        float4* packed = (float4*)d_ws;
        float2* seedtab = (float2*)((char*)d_ws + packed_bytes);
        const int total = NDIM * (NBINS - 1);
        hipLaunchKernelGGL(mg_pack, dim3((total + 255) / 256), dim3(256), 0, stream,
                           xvals, cdf, packed, seedtab);
        hipLaunchKernelGGL((mg_main<true>), mainGrid, mainBlock, 0, stream,
                           x, xvals, cdf, packed, seedtab, out, B);
    } else {
        hipLaunchKernelGGL((mg_main<false>), mainGrid, mainBlock, 0, stream,
                           x, xvals, cdf, (const float4*)nullptr, (const float2*)nullptr, out, B);
    }
}

// Round 3
// 160.402 us; speedup vs baseline: 1.9771x; 1.2859x over previous
//
#include <hip/hip_runtime.h>
#include <math.h>

#define NBINS 1000
#define NDIM 64
#define DIMS_PER_BLOCK 8
#define DIM_GROUPS (NDIM / DIMS_PER_BLOCK)      // 8
#define BLOCK_THREADS 1024
#define ROWS_PER_ITER (BLOCK_THREADS / 2)       // 512 rows per block-iteration
#define ROW_BLOCKS 256                           // %8==0 -> same-XCD dim-groups

// zero the log_det region (re-poisoned 0xAA before every timed launch)
__global__ __launch_bounds__(1024) void mg_zero(float* __restrict__ p, int n) {
    int i = blockIdx.x * blockDim.x + threadIdx.x;
    if (i < n) p[i] = 0.0f;
}

// Block owns DIMS_PER_BLOCK dims; knots (x_i, c_i) staged in LDS (64 KB).
// Thread handles 4 dims of one row; 2 threads per row. log_det accumulated
// via one atomicAdd per thread-pair per row (8 partials per row total).
__global__ __launch_bounds__(BLOCK_THREADS, 8)
void mg_main(const float* __restrict__ x,
             const float* __restrict__ xvals,
             const float* __restrict__ cdf,
             float* __restrict__ out, int B) {
    __shared__ float2 knots[DIMS_PER_BLOCK * NBINS];   // 64000 B

    const int dimbase = blockIdx.y * DIMS_PER_BLOCK;

    // cooperative stage: coalesced reads of this block's 8-dim slice
    for (int k = threadIdx.x; k < DIMS_PER_BLOCK * NBINS; k += BLOCK_THREADS)
        knots[k] = make_float2(xvals[dimbase * NBINS + k], cdf[dimbase * NBINS + k]);
    __syncthreads();

    const int dl = (threadIdx.x & 1) * 4;              // local dims dl..dl+3
    const int qidx = blockIdx.y * 2 + (threadIdx.x & 1); // float4 index within row

    // per-dim seeds, hoisted out of the row loop (reused for all rows)
    float lo[4], invstep[4];
#pragma unroll
    for (int j = 0; j < 4; ++j) {
        float l = knots[(dl + j) * NBINS].x;
        float h = knots[(dl + j) * NBINS + NBINS - 1].x;
        lo[j] = l;
        invstep[j] = (float)(NBINS - 1) / (h - l);
    }

    for (int row = blockIdx.x * ROWS_PER_ITER + (threadIdx.x >> 1);
         row < B; row += gridDim.x * ROWS_PER_ITER) {

        const float4 xq = ((const float4*)x)[(size_t)row * (NDIM / 4) + qidx];
        float xv[4] = {xq.x, xq.y, xq.z, xq.w};

        // seed indices, then all gathers issued together (ILP for LDS latency)
        int ii[4];
        float2 kl[4], kr[4];
#pragma unroll
        for (int j = 0; j < 4; ++j) {
            int i = (int)((xv[j] - lo[j]) * invstep[j]);   // trunc; clamp+walk fix
            ii[j] = min(max(i, 0), NBINS - 2);
        }
#pragma unroll
        for (int j = 0; j < 4; ++j) {
            kl[j] = knots[(dl + j) * NBINS + ii[j]];
            kr[j] = knots[(dl + j) * NBINS + ii[j] + 1];
        }

        float z4[4], ph[4], sumsq = 0.0f;
#pragma unroll
        for (int j = 0; j < 4; ++j) {
            int i = ii[j];
            float2 a = kl[j], b = kr[j];
            // exact searchsorted(side='left') fix-up walk (rarely taken)
            while (xv[j] > b.x && i < NBINS - 2) {
                ++i; a = b; b = knots[(dl + j) * NBINS + i + 1];
            }
            while (xv[j] <= a.x && i > 0) {
                --i; b = a; a = knots[(dl + j) * NBINS + i];
            }

            float denom = (b.x - a.x) + 1e-12f;
            float slope = (b.y - a.y) * __builtin_amdgcn_rcpf(denom);
            float u = fmaf(slope, xv[j] - a.x, a.y);
            ph[j] = fmaxf(slope, 1e-12f);
            u = fminf(fmaxf(u, 1e-6f), 1.0f - 1e-6f);
            float e1 = fminf(fmaxf(fmaf(2.0f, u, -1.0f), -0.99999f), 0.99999f);

            // Giles (2012) erfinv; tail poly wave-divergent (rare)
            float wv = -__logf(fmaf(-e1, e1, 1.0f));
            float t = wv - 2.5f;
            float p = 2.81022636e-08f;
            p = fmaf(p, t, 3.43273939e-07f);
            p = fmaf(p, t, -3.5233877e-06f);
            p = fmaf(p, t, -4.39150654e-06f);
            p = fmaf(p, t, 0.00021858087f);
            p = fmaf(p, t, -0.00125372503f);
            p = fmaf(p, t, -0.00417768164f);
            p = fmaf(p, t, 0.246640727f);
            p = fmaf(p, t, 1.50140941f);
            if (wv >= 5.0f) {
                float tq = sqrtf(wv) - 3.0f;
                float pt = -0.000200214257f;
                pt = fmaf(pt, tq, 0.000100950558f);
                pt = fmaf(pt, tq, 0.00134934322f);
                pt = fmaf(pt, tq, -0.00367342844f);
                pt = fmaf(pt, tq, 0.00573950773f);
                pt = fmaf(pt, tq, -0.0076224613f);
                pt = fmaf(pt, tq, 0.00943887047f);
                pt = fmaf(pt, tq, 1.00167406f);
                pt = fmaf(pt, tq, 2.83297682f);
                p = pt;
            }
            float z = 1.4142135623730951f * p * e1;
            z = fminf(fmaxf(z, -10.0f), 10.0f);
            z4[j] = z;
            sumsq = fmaf(z, z, sumsq);
        }

        ((float4*)out)[(size_t)row * (NDIM / 4) + qidx] =
            make_float4(z4[0], z4[1], z4[2], z4[3]);

        // term = sum_j [log(p_hat_j) + 0.5 z^2 + log(sqrt(2pi))]
        // pairwise products: safe (>=1e-24 >> fp32 min normal), halves the logs.
        // -log(phi+1e-12) == 0.5 z^2 + 0.9189385 to 4.3e-8 abs since |z|<=4.417.
        float term = fmaf(0.5f, sumsq, 4.0f * 0.9189385332046727f)
                   + __logf(ph[0] * ph[1]) + __logf(ph[2] * ph[3]);

        term += __shfl_xor(term, 1, 64);   // partner lane covers the other 4 dims
        if ((threadIdx.x & 1) == 0)
            atomicAdd(out + (size_t)B * NDIM + row, term);
    }
}

extern "C" void kernel_launch(void* const* d_in, const int* in_sizes, int n_in,
                              void* d_out, int out_size, void* d_ws, size_t ws_size,
                              hipStream_t stream) {
    const float* x = (const float*)d_in[0];
    const float* xvals = (const float*)d_in[1];
    const float* cdf = (const float*)d_in[2];
    float* out = (float*)d_out;
    int B = in_sizes[0] / NDIM;

    hipLaunchKernelGGL(mg_zero, dim3((B + 1023) / 1024), dim3(1024), 0, stream,
                       out + (size_t)B * NDIM, B);
    hipLaunchKernelGGL(mg_main, dim3(ROW_BLOCKS, DIM_GROUPS), dim3(BLOCK_THREADS),
                       0, stream, x, xvals, cdf, out, B);
}